// Round 3
// baseline (215.308 us; speedup 1.0000x reference)
//
#include <hip/hip_runtime.h>
#include <stdint.h>

#define N_NODES 100000
#define D_FEAT  128
#define N_EDGES 500000
#define HIDDEN  256
#define EPT     64                                   // edges per tile
#define NTILES  ((N_EDGES + EPT - 1) / EPT)          // 7813
#define GRID_MAIN 256

typedef __bf16 bf16x8 __attribute__((ext_vector_type(8)));
typedef __bf16 bf16x4 __attribute__((ext_vector_type(4)));
typedef float  f32x4  __attribute__((ext_vector_type(4)));

__device__ __forceinline__ void gld_lds16(const unsigned short* g, unsigned char* l) {
  __builtin_amdgcn_global_load_lds(
      (const __attribute__((address_space(1))) unsigned int*)g,
      (__attribute__((address_space(3))) unsigned int*)l, 16, 0, 0);
}

__device__ __forceinline__ bf16x8 cvt8(f32x4 lo, f32x4 hi) {
  bf16x8 r;
  r[0] = (__bf16)lo[0]; r[1] = (__bf16)lo[1]; r[2] = (__bf16)lo[2]; r[3] = (__bf16)lo[3];
  r[4] = (__bf16)hi[0]; r[5] = (__bf16)hi[1]; r[6] = (__bf16)hi[2]; r[7] = (__bf16)hi[3];
  return r;
}

// z (f32) -> bf16, vectorized
__global__ void cvt_z(const float* __restrict__ src, unsigned short* __restrict__ dst, int n4) {
  int i = blockIdx.x * blockDim.x + threadIdx.x;
  const int stride = gridDim.x * blockDim.x;
  for (; i < n4; i += stride) {
    const f32x4 v = ((const f32x4*)src)[i];
    bf16x4 o;
    o[0] = (__bf16)v[0]; o[1] = (__bf16)v[1]; o[2] = (__bf16)v[2]; o[3] = (__bf16)v[3];
    ((bf16x4*)dst)[i] = o;
  }
}

// xT = relu(W1 * concatT + b1); out = sigmoid(w2 . x + b2)
// 8 waves: w = ng*2 + mg; wave owns hidden rows [ng*64, ng*64+64), edges [mg*32, mg*32+32).
// LDS feature tile is K-MAJOR: 16B unit at sbuf[c*1024 + m*16] = F[m][8c..8c+7],
// staged linearly by global_load_lds (chunk c per instruction, lane = edge m).
__global__ __launch_bounds__(512, 2)
void mlp_main(const int* __restrict__ eidx,
              const unsigned short* __restrict__ z16,   // [N_NODES][128] bf16
              const float* __restrict__ w1f,            // [256][256] f32
              const float* __restrict__ b1,
              const float* __restrict__ w2g,
              const float* __restrict__ b2,
              float* __restrict__ out) {
  __shared__ unsigned char sbuf[3][EPT * 512];          // 3 x 32 KiB
  __shared__ float red[2][4][72];                       // parity x ng x edge(padded)

  const int tid  = threadIdx.x;
  const int w    = tid >> 6;         // wave 0..7
  const int l    = tid & 63;
  const int l15  = l & 15;
  const int g    = l >> 4;           // k-slice group 0..3
  const int ng   = w >> 1;           // hidden group (64 rows)
  const int mg   = w & 1;            // edge group (32 edges)
  const int half = w >> 2;           // staging: 0 = row-node chunks, 1 = col-node

  const int is64 = (eidx[1] == 0 && eidx[3] == 0 && eidx[5] == 0);
  const float b2v = b2[0];

  // ---- A fragments (W1, f32 -> bf16), register-resident: 128 VGPR ----
  // A[n][k]: n = ng*64 + nt*16 + (l&15), k = ks*32 + g*8 .. +7
  bf16x8 a[4][8];
  #pragma unroll
  for (int nt = 0; nt < 4; ++nt) {
    const int n = ng * 64 + nt * 16 + l15;
    #pragma unroll
    for (int ks = 0; ks < 8; ++ks) {
      const int k = ks * 32 + g * 8;
      const f32x4 lo = *(const f32x4*)(w1f + n * 256 + k);
      const f32x4 hi = *(const f32x4*)(w1f + n * 256 + k + 4);
      a[nt][ks] = cvt8(lo, hi);
    }
  }
  // bias / fc2 weights for this lane's accumulator rows (C/D row = g*4 + r)
  f32x4 b1v[4], w2v[4];
  #pragma unroll
  for (int nt = 0; nt < 4; ++nt) {
    const int nb = ng * 64 + nt * 16 + g * 4;
    b1v[nt] = *(const f32x4*)(b1 + nb);
    w2v[nt] = *(const f32x4*)(w2g + nb);
  }

  // per-lane node index for this wave's staging half, tile t
  auto ldidx = [&](int t) -> int {
    int e = t * EPT + l;
    if (e > N_EDGES - 1) e = N_EDGES - 1;
    return is64 ? eidx[6 * e + 2 + 2 * half] : eidx[3 * e + 1 + half];
  };
  // stage one tile: wave w issues chunks 4w..4w+3 (1024B each, linear dest)
  auto stage = [&](int buf, int iv) {
    const unsigned short* src = z16 + (size_t)iv * D_FEAT;
    #pragma unroll
    for (int j = 0; j < 4; ++j) {
      const int c = 4 * w + j;
      gld_lds16(src + ((c & 15) << 3), &sbuf[buf][c << 10]);
    }
  };

  // ---- prologue ----
  const int t0 = blockIdx.x;
  int ivq = ldidx(t0);
  stage(0, ivq);                       // compiler waits idx before addr use
  int iv_next = ldidx(t0 + GRID_MAIN);

  int cb = 0, it = 0;
  for (int t = t0; t < NTILES; t += GRID_MAIN, ++it) {
    __syncthreads();                   // vmcnt drain: all waited loads >=1 iter old

    // stage tile t+1 into next buffer; prefetch idx for t+2
    int cn = cb + 1; if (cn == 3) cn = 0;
    stage(cn, iv_next);
    iv_next = ldidx(t + 2 * GRID_MAIN);

    // deferred output for tile t-1 (red written before this barrier)
    if (it) {
      if (w < 4) {
        const int e = (w << 4) + (l >> 2);
        float v = red[(it - 1) & 1][l & 3][e];
        v += __shfl_xor(v, 1);
        v += __shfl_xor(v, 2);
        const int eg = (t - GRID_MAIN) * EPT + e;
        if ((l & 3) == 0 && eg < N_EDGES)
          out[eg] = 1.f / (1.f + __expf(-(v + b2v)));
      }
    }

    // ---- MFMA: D[n][m] += sum_k A[n][k] * F[m][k] on buf cb ----
    f32x4 acc[4][2];
    #pragma unroll
    for (int nt = 0; nt < 4; ++nt) {
      acc[nt][0] = (f32x4){0.f, 0.f, 0.f, 0.f};
      acc[nt][1] = (f32x4){0.f, 0.f, 0.f, 0.f};
    }
    const unsigned char* sb = &sbuf[cb][0];
    #pragma unroll
    for (int ks = 0; ks < 8; ++ks) {
      bf16x8 bf[2];
      #pragma unroll
      for (int ct = 0; ct < 2; ++ct) {
        const int c = ks * 4 + g;                      // k-chunk
        const int m = mg * 32 + ct * 16 + l15;         // edge
        bf[ct] = *(const bf16x8*)(sb + (c << 10) + (m << 4));
      }
      __builtin_amdgcn_s_setprio(1);
      #pragma unroll
      for (int nt = 0; nt < 4; ++nt)
        #pragma unroll
        for (int ct = 0; ct < 2; ++ct)
          acc[nt][ct] = __builtin_amdgcn_mfma_f32_16x16x32_bf16(
              a[nt][ks], bf[ct], acc[nt][ct], 0, 0, 0);
      __builtin_amdgcn_s_setprio(0);
    }

    // ---- epilogue: bias + relu + fc2 partial ----
    float p[2] = {0.f, 0.f};
    #pragma unroll
    for (int nt = 0; nt < 4; ++nt) {
      #pragma unroll
      for (int r = 0; r < 4; ++r) {
        const float bb = b1v[nt][r], ww = w2v[nt][r];
        #pragma unroll
        for (int ct = 0; ct < 2; ++ct) {
          float x = acc[nt][ct][r] + bb;               // n = ng*64+nt*16+g*4+r
          x = fmaxf(x, 0.f);
          p[ct] = fmaf(x, ww, p[ct]);
        }
      }
    }
    #pragma unroll
    for (int ct = 0; ct < 2; ++ct) {                   // sum over 4 g-groups
      p[ct] += __shfl_xor(p[ct], 16);
      p[ct] += __shfl_xor(p[ct], 32);
    }
    if (l < 16) {
      red[it & 1][ng][mg * 32 + l]      = p[0];
      red[it & 1][ng][mg * 32 + 16 + l] = p[1];
    }
    cb = cn;
  }

  // ---- tail: output last tile ----
  __syncthreads();
  {
    const int tl = t0 + (it - 1) * GRID_MAIN;
    if (w < 4) {
      const int e = (w << 4) + (l >> 2);
      float v = red[(it - 1) & 1][l & 3][e];
      v += __shfl_xor(v, 1);
      v += __shfl_xor(v, 2);
      const int eg = tl * EPT + e;
      if ((l & 3) == 0 && eg < N_EDGES)
        out[eg] = 1.f / (1.f + __expf(-(v + b2v)));
    }
  }
}

extern "C" void kernel_launch(void* const* d_in, const int* in_sizes, int n_in,
                              void* d_out, int out_size, void* d_ws, size_t ws_size,
                              hipStream_t stream) {
  const float* z    = (const float*)d_in[0];
  const int*   eidx = (const int*)d_in[1];
  const float* fc1w = (const float*)d_in[2];
  const float* fc1b = (const float*)d_in[3];
  const float* fc2w = (const float*)d_in[4];
  const float* fc2b = (const float*)d_in[5];
  float* out = (float*)d_out;

  unsigned short* z16 = (unsigned short*)d_ws;   // 25.6 MB bf16 copy of z

  cvt_z<<<2048, 256, 0, stream>>>(z, z16, N_NODES * D_FEAT / 4);
  mlp_main<<<GRID_MAIN, 512, 0, stream>>>(eidx, z16, fc1w, fc1b, fc2w, fc2b, out);
}